// Round 9
// baseline (587.862 us; speedup 1.0000x reference)
//
#include <hip/hip_runtime.h>
#include <math.h>

#define SCALE_F 0.0721687836487032f  // 192^-0.5

typedef __attribute__((ext_vector_type(8))) short bf16x8;
typedef __attribute__((ext_vector_type(4))) float f32x4;
typedef __attribute__((ext_vector_type(4))) unsigned short u16x4;

static __device__ __forceinline__ short f2bf(float f) {
  unsigned u = __float_as_uint(f);
  u += 0x7fffu + ((u >> 16) & 1u);   // RNE
  return (short)(u >> 16);
}

// async global->LDS, 16B per lane (m97-verified path)
static __device__ __forceinline__ void gl_lds16(const void* g, void* l) {
  __builtin_amdgcn_global_load_lds((const __attribute__((address_space(1))) void*)g,
                                   (__attribute__((address_space(3))) void*)l, 16, 0, 0);
}

// ---------------------------------------------------------------------------
// bf16 MFMA GEMM (m97 structure): C[M,N] = A[M,K] @ W[N,K]^T
// MODE 0: fp32 out row-major [M][N]
// MODE 2: q_up fused rope+scale+pack -> Qb (b,h,s,192) bf16   (N=3072)
// MODE 3: kv_up fused split -> Kb (b,h,s,192) nope cols + Vrow (b,h,s,128)
// ---------------------------------------------------------------------------
template <int MODE>
__global__ __launch_bounds__(256) void gemm_mfma(
    const short* __restrict__ A, const short* __restrict__ W,
    void* __restrict__ Cout, int N, int K,
    const float* __restrict__ cosb, const float* __restrict__ sinb,
    short* __restrict__ out2)
{
  __shared__ __align__(16) short As[128 * 32];
  __shared__ __align__(16) short Ws[128 * 32];
  const int tid = threadIdx.x;
  const int lane = tid & 63;
  const int quad = lane >> 4, n16 = lane & 15;
  const int bm = blockIdx.y * 128, bn = blockIdx.x * 128;
  const int wr = ((tid >> 6) >> 1) * 64, wc = ((tid >> 6) & 1) * 64;

  f32x4 acc[4][4];
  #pragma unroll
  for (int i = 0; i < 4; ++i)
    #pragma unroll
    for (int j = 0; j < 4; ++j) acc[i][j] = (f32x4){0.f, 0.f, 0.f, 0.f};

  const int r0 = tid >> 2, c0 = (tid & 3) * 8;
  const short* a0p = A + (size_t)(bm + r0) * K + c0;
  const short* a1p = A + (size_t)(bm + 64 + r0) * K + c0;
  const short* w0p = W + (size_t)(bn + r0) * K + c0;
  const short* w1p = W + (size_t)(bn + 64 + r0) * K + c0;
  short* asd0 = &As[tid * 8];
  short* asd1 = &As[2048 + tid * 8];
  short* wsd0 = &Ws[tid * 8];
  short* wsd1 = &Ws[2048 + tid * 8];

  for (int k0 = 0; k0 < K; k0 += 32) {
    gl_lds16(a0p, asd0);
    gl_lds16(a1p, asd1);
    gl_lds16(w0p, wsd0);
    gl_lds16(w1p, wsd1);
    a0p += 32; a1p += 32; w0p += 32; w1p += 32;
    __syncthreads();

    bf16x8 af[4], wf[4];
    #pragma unroll
    for (int i = 0; i < 4; ++i) {
      af[i] = *(const bf16x8*)&As[(wr + i * 16 + n16) * 32 + quad * 8];
      wf[i] = *(const bf16x8*)&Ws[(wc + i * 16 + n16) * 32 + quad * 8];
    }
    #pragma unroll
    for (int i = 0; i < 4; ++i)
      #pragma unroll
      for (int j = 0; j < 4; ++j)
        acc[i][j] = __builtin_amdgcn_mfma_f32_16x16x32_bf16(af[i], wf[j], acc[i][j], 0, 0, 0);
    __syncthreads();
  }

  if (MODE == 0) {
    #pragma unroll
    for (int i = 0; i < 4; ++i)
      #pragma unroll
      for (int r = 0; r < 4; ++r) {
        size_t row = (size_t)(bm + wr + i * 16 + quad * 4 + r);
        #pragma unroll
        for (int j = 0; j < 4; ++j)
          ((float*)Cout)[row * N + bn + wc + j * 16 + n16] = acc[i][j][r];
      }
  } else if (MODE == 2) {
    // q_up: rope last 64 of each 192-head, scale, pack to (b,h,s,192)
    #pragma unroll
    for (int i = 0; i < 4; ++i)
      #pragma unroll
      for (int r = 0; r < 4; ++r) {
        int m = bm + wr + i * 16 + quad * 4 + r;
        int bb = m >> 11, s = m & 2047;
        #pragma unroll
        for (int j = 0; j < 4; ++j) {
          int col = bn + wc + j * 16 + n16;
          int h = col / 192, c = col - h * 192;
          float v = acc[i][j][r];
          if (c >= 128) {
            int jr = c - 128;
            float part = acc[i][j ^ 2][r];   // partner col = col +/- 32 (in-wave)
            float cs = cosb[(size_t)m * 64 + jr], sn = sinb[(size_t)m * 64 + jr];
            v = (jr < 32) ? (v * cs - part * sn) : (v * cs + part * sn);
          }
          ((short*)Cout)[(((size_t)(bb * 16 + h)) * 2048 + s) * 192 + c] = f2bf(v * SCALE_F);
        }
      }
  } else {
    // kv_up: N=4096, head = col>>8; c<128 -> Kb nope, c>=128 -> Vrow (b,h,s,128)
    #pragma unroll
    for (int i = 0; i < 4; ++i)
      #pragma unroll
      for (int r = 0; r < 4; ++r) {
        int m = bm + wr + i * 16 + quad * 4 + r;
        int bb = m >> 11, s = m & 2047;
        #pragma unroll
        for (int j = 0; j < 4; ++j) {
          int col = bn + wc + j * 16 + n16;
          int h = col >> 8, c = col & 255;
          short v = f2bf(acc[i][j][r]);
          if (c < 128)
            ((short*)Cout)[(((size_t)(bb * 16 + h)) * 2048 + s) * 192 + c] = v;
          else
            out2[((size_t)(bb * 16 + h) * 2048 + s) * 128 + (c - 128)] = v;
        }
      }
  }
}

// ---------------------------------------------------------------------------
// fused fp32 -> bf16 cast of hidden + all 5 weights (one launch)
// ---------------------------------------------------------------------------
__global__ __launch_bounds__(256) void cast_all(
    const float* __restrict__ hidden, const float* __restrict__ Wqd,
    const float* __restrict__ Wqu, const float* __restrict__ Wkvu,
    const float* __restrict__ Wo, const float* __restrict__ Wkvd,
    short* __restrict__ hb, short* __restrict__ Wqd_b, short* __restrict__ Wqu_b,
    short* __restrict__ Wkvu_b, short* __restrict__ Wo_b, short* __restrict__ Wkvd_b)
{
  int blk = blockIdx.x;
  const float* src; short* dst; int i;
  if (blk < 8192)       { src = hidden; dst = hb;     i = (blk * 256 + threadIdx.x) * 4; }
  else if (blk < 11264) { src = Wqd;  dst = Wqd_b;  i = ((blk - 8192) * 256 + threadIdx.x) * 4; }
  else if (blk < 15872) { src = Wqu;  dst = Wqu_b;  i = ((blk - 11264) * 256 + threadIdx.x) * 4; }
  else if (blk < 17920) { src = Wkvu; dst = Wkvu_b; i = ((blk - 15872) * 256 + threadIdx.x) * 4; }
  else if (blk < 22016) { src = Wo;   dst = Wo_b;   i = ((blk - 17920) * 256 + threadIdx.x) * 4; }
  else {
    i = ((blk - 22016) * 256 + threadIdx.x) * 4;
    int r = i >> 11;
    short4 o = {0, 0, 0, 0};
    if (r < 576) {
      float4 v = *(const float4*)(Wkvd + i);
      o.x = f2bf(v.x); o.y = f2bf(v.y); o.z = f2bf(v.z); o.w = f2bf(v.w);
    }
    *(short4*)(Wkvd_b + i) = o;
    return;
  }
  float4 v = *(const float4*)(src + i);
  short4 o = { f2bf(v.x), f2bf(v.y), f2bf(v.z), f2bf(v.w) };
  *(short4*)(dst + i) = o;
}

// ---------------------------------------------------------------------------
__global__ __launch_bounds__(256) void rmsnorm_cast(
    const float* __restrict__ X, const float* __restrict__ gamma,
    short* __restrict__ Y, int C, int sx, int sy)
{
  const float* x = X + (size_t)blockIdx.x * sx;
  short* y = Y + (size_t)blockIdx.x * sy;
  const int tid = threadIdx.x;
  float ss = 0.f;
  for (int c = tid * 4; c < C; c += 1024) {
    float4 v = *(const float4*)(x + c);
    ss += v.x * v.x + v.y * v.y + v.z * v.z + v.w * v.w;
  }
  #pragma unroll
  for (int off = 32; off > 0; off >>= 1) ss += __shfl_down(ss, off, 64);
  __shared__ float red[4];
  if ((tid & 63) == 0) red[tid >> 6] = ss;
  __syncthreads();
  float tot = red[0] + red[1] + red[2] + red[3];
  float scale = rsqrtf(tot / (float)C + 1e-6f);
  for (int c = tid * 4; c < C; c += 1024) {
    float4 v = *(const float4*)(x + c);
    float4 g = *(const float4*)(gamma + c);
    short4 o = { f2bf(v.x * scale * g.x), f2bf(v.y * scale * g.y),
                 f2bf(v.z * scale * g.z), f2bf(v.w * scale * g.w) };
    *(short4*)(y + c) = o;
  }
}

// ---------------------------------------------------------------------------
__global__ __launch_bounds__(256) void rmsnorm_kv_rope(
    const float* __restrict__ kvf, const float* __restrict__ gamma,
    const float* __restrict__ cosb, const float* __restrict__ sinb,
    short* __restrict__ ckv, short* __restrict__ kr)
{
  const int m = blockIdx.x;
  const float* x = kvf + (size_t)m * 640;
  short* y = ckv + (size_t)m * 512;
  const int tid = threadIdx.x;
  float ss = 0.f;
  for (int c = tid * 4; c < 512; c += 1024) {
    float4 v = *(const float4*)(x + c);
    ss += v.x * v.x + v.y * v.y + v.z * v.z + v.w * v.w;
  }
  #pragma unroll
  for (int off = 32; off > 0; off >>= 1) ss += __shfl_down(ss, off, 64);
  __shared__ float red[4];
  if ((tid & 63) == 0) red[tid >> 6] = ss;
  __syncthreads();
  float tot = red[0] + red[1] + red[2] + red[3];
  float scale = rsqrtf(tot / 512.f + 1e-6f);
  for (int c = tid * 4; c < 512; c += 1024) {
    float4 v = *(const float4*)(x + c);
    float4 g = *(const float4*)(gamma + c);
    short4 o = { f2bf(v.x * scale * g.x), f2bf(v.y * scale * g.y),
                 f2bf(v.z * scale * g.z), f2bf(v.w * scale * g.w) };
    *(short4*)(y + c) = o;
  }
  if (tid < 32) {
    const float* cb = cosb + (size_t)m * 64;
    const float* sb = sinb + (size_t)m * 64;
    float x1 = x[512 + tid], x2 = x[512 + tid + 32];
    kr[(size_t)m * 64 + tid]      = f2bf(x1 * cb[tid] - x2 * sb[tid]);
    kr[(size_t)m * 64 + tid + 32] = f2bf(x2 * cb[tid + 32] + x1 * sb[tid + 32]);
  }
}

// ---------------------------------------------------------------------------
__global__ __launch_bounds__(256) void krope_fill(
    const short* __restrict__ kr, short* __restrict__ Kb)
{
  int m = blockIdx.x;
  int b = m >> 11, s = m & 2047;
  for (int idx = threadIdx.x; idx < 1024; idx += 256) {
    int h = idx >> 6, j = idx & 63;
    Kb[(((size_t)(b * 16 + h)) * 2048 + s) * 192 + 128 + j] = kr[(size_t)m * 64 + j];
  }
}

// ---------------------------------------------------------------------------
// Vrow (b,h,s,128) -> Vt (b,h,128,2048), coalesced both sides via LDS tile
// ---------------------------------------------------------------------------
__global__ __launch_bounds__(256) void pack_vt(
    const short* __restrict__ Vrow, short* __restrict__ Vt)
{
  __shared__ short t[32][34];
  int s0 = blockIdx.x * 32, v0 = blockIdx.y * 32, bh = blockIdx.z;
  int c = threadIdx.x & 31, r4 = threadIdx.x >> 5;
  #pragma unroll
  for (int rr = 0; rr < 32; rr += 8) {
    int s = s0 + rr + r4;
    t[rr + r4][c] = Vrow[((size_t)bh * 2048 + s) * 128 + v0 + c];
  }
  __syncthreads();
  #pragma unroll
  for (int rr = 0; rr < 32; rr += 8) {
    int v = v0 + rr + r4;
    Vt[((size_t)bh * 128 + v) * 2048 + s0 + c] = t[c][rr + r4];
  }
}

// ---------------------------------------------------------------------------
// MFMA flash attention v7: 2-wave blocks (128 thr), wave = 64 q-rows (4 rg).
// Each K-frag LDS read feeds 4 MFMAs (2x better than v6); Q/O register-
// resident (~340 VGPR, 1 wave/SIMD); LDS 50.2 KB -> 2 blocks/CU; grid 512
// heavy-first for backfill. S^T formulation + fixed-shift softmax retained.
// P buffer per wave = 32 rows, reused across the two rg-pairs (same-wave
// lgkm ordering, no barrier needed).
// ---------------------------------------------------------------------------
#define PSTR 72

__global__ __launch_bounds__(128, 1) void flash_mfma(
    const short* __restrict__ Qb, const short* __restrict__ Kb,
    const short* __restrict__ Vt, short* __restrict__ attnb)
{
  __shared__ __align__(16) short KsF[24 * 512];     // 24.6 KB, frag order
  __shared__ __align__(16) short VsF[16 * 512];     // 16.4 KB
  __shared__ __align__(16) short Ps[2][32 * PSTR];  // 9.2 KB   (total 50.2 KB)

  const int h = blockIdx.x;                         // XCD locality
  const int qt = (gridDim.y - 1) - blockIdx.y;      // heavy q-tiles first
  const int b = blockIdx.z;
  const int bh = b * 16 + h;
  const int tid = threadIdx.x;
  const int wave = tid >> 6, lane = tid & 63;
  const int quad = lane >> 4, n16 = lane & 15;
  const int lq = lane >> 2, lr = lane & 3;          // staging lane split
  const int qw = qt * 128 + wave * 64;              // wave's first q-row
  const int nkt = 2 * qt + 2;

  // Q frags (B operand for S^T): 4 row-groups x 6 k-slices, register resident
  bf16x8 aQ[4][6];
  #pragma unroll
  for (int rg = 0; rg < 4; ++rg) {
    const short* qp = Qb + ((size_t)bh * 2048 + qw + rg * 16 + n16) * 192 + quad * 8;
    #pragma unroll
    for (int t = 0; t < 6; ++t) aQ[rg][t] = *(const bf16x8*)(qp + t * 32);
  }

  f32x4 O[4][8];
  #pragma unroll
  for (int rg = 0; rg < 4; ++rg)
    #pragma unroll
    for (int i = 0; i < 8; ++i) O[rg][i] = (f32x4){0.f, 0.f, 0.f, 0.f};
  float lp[4] = {0.f, 0.f, 0.f, 0.f};

  short* pw = &Ps[wave][0];

  for (int kt = 0; kt < nkt; ++kt) {
    // ---- stage K (24 chunks) and V^T (16 chunks), 2 waves split ----
    {
      #pragma unroll
      for (int u = 0; u < 12; ++u) {
        int ci = wave * 12 + u, ct = ci / 6, t = ci % 6;
        gl_lds16(Kb + ((size_t)bh * 2048 + kt * 64 + ct * 16 + lq) * 192 + t * 32 + lr * 8,
                 &KsF[ci * 512 + lane * 8]);
      }
      #pragma unroll
      for (int u = 0; u < 8; ++u) {
        int ci = wave * 8 + u, ks = ci >> 3, vt = ci & 7;
        gl_lds16(Vt + ((size_t)bh * 128 + vt * 16 + lq) * 2048 + kt * 64 + ks * 32 + lr * 8,
                 &VsF[ci * 512 + lane * 8]);
      }
    }
    __syncthreads();   // drain DMA

    if (kt * 64 <= qw + 63) {
      const bool tail = (kt * 64 + 63 > qw);
      bool act[4];
      f32x4 s4[4][4];   // [rg][ct]
      #pragma unroll
      for (int ct = 0; ct < 4; ++ct) {
        act[ct] = (kt * 64 + ct * 16 <= qw + 63);
        if (act[ct]) {
          f32x4 a0 = (f32x4){0.f,0.f,0.f,0.f}, a1 = a0, a2 = a0, a3 = a0;
          #pragma unroll
          for (int t = 0; t < 6; ++t) {
            bf16x8 ak = *(const bf16x8*)&KsF[(ct * 6 + t) * 512 + n16 * 32 + quad * 8];
            a0 = __builtin_amdgcn_mfma_f32_16x16x32_bf16(ak, aQ[0][t], a0, 0, 0, 0);
            a1 = __builtin_amdgcn_mfma_f32_16x16x32_bf16(ak, aQ[1][t], a1, 0, 0, 0);
            a2 = __builtin_amdgcn_mfma_f32_16x16x32_bf16(ak, aQ[2][t], a2, 0, 0, 0);
            a3 = __builtin_amdgcn_mfma_f32_16x16x32_bf16(ak, aQ[3][t], a3, 0, 0, 0);
          }
          s4[0][ct] = a0; s4[1][ct] = a1; s4[2][ct] = a2; s4[3][ct] = a3;
        }
      }

      // ---- two rg-pair phases: exp+mask+P-store then PV ----
      #pragma unroll
      for (int p = 0; p < 2; ++p) {
        #pragma unroll
        for (int rgl = 0; rgl < 2; ++rgl) {
          const int rg = p * 2 + rgl;
          const int q = qw + rg * 16 + n16;
          #pragma unroll
          for (int ct = 0; ct < 4; ++ct) {
            u16x4 pk;
            #pragma unroll
            for (int r = 0; r < 4; ++r) {
              float v = 0.f;
              if (act[ct]) {
                v = __expf(s4[rg][ct][r]);
                if (tail) {
                  int key = kt * 64 + ct * 16 + quad * 4 + r;
                  if (key > q) v = 0.f;
                }
              }
              lp[rg] += v;
              pk[r] = (unsigned short)f2bf(v);
            }
            *(u16x4*)&pw[(rgl * 16 + n16) * PSTR + ct * 16 + quad * 4] = pk;
          }
        }
        #pragma unroll
        for (int ks = 0; ks < 2; ++ks) {
          if (kt * 64 + ks * 32 <= qw + 63) {
            bf16x8 aP0 = *(const bf16x8*)&pw[(n16) * PSTR + ks * 32 + quad * 8];
            bf16x8 aP1 = *(const bf16x8*)&pw[(16 + n16) * PSTR + ks * 32 + quad * 8];
            #pragma unroll
            for (int vt = 0; vt < 8; ++vt) {
              bf16x8 bV = *(const bf16x8*)&VsF[(ks * 8 + vt) * 512 + n16 * 32 + quad * 8];
              O[p * 2][vt]     = __builtin_amdgcn_mfma_f32_16x16x32_bf16(aP0, bV, O[p * 2][vt], 0, 0, 0);
              O[p * 2 + 1][vt] = __builtin_amdgcn_mfma_f32_16x16x32_bf16(aP1, bV, O[p * 2 + 1][vt], 0, 0, 0);
            }
          }
        }
      }
    }
    __syncthreads();   // protect K/V buffers before next iter's DMA
  }

  // ---- epilogue: reduce l over quads, scale, store ----
  #pragma unroll
  for (int rg = 0; rg < 4; ++rg) {
    float l = lp[rg];
    l += __shfl_xor(l, 16);
    l += __shfl_xor(l, 32);          // lanes 0..15 hold l for q-col n16
    float inv_l[4];
    #pragma unroll
    for (int r = 0; r < 4; ++r)
      inv_l[r] = 1.f / __shfl(l, quad * 4 + r);
    #pragma unroll
    for (int vt = 0; vt < 8; ++vt)
      #pragma unroll
      for (int r = 0; r < 4; ++r) {
        size_t m = (size_t)b * 2048 + qw + rg * 16 + quad * 4 + r;
        attnb[(m * 16 + h) * 128 + vt * 16 + n16] = f2bf(O[rg][vt][r] * inv_l[r]);
      }
  }
}

// ---------------------------------------------------------------------------
extern "C" void kernel_launch(void* const* d_in, const int* in_sizes, int n_in,
                              void* d_out, int out_size, void* d_ws, size_t ws_size,
                              hipStream_t stream)
{
  const float* hidden   = (const float*)d_in[0];
  const float* cosb     = (const float*)d_in[1];
  const float* sinb     = (const float*)d_in[2];
  const float* Wq_down  = (const float*)d_in[3];
  const float* q_gamma  = (const float*)d_in[4];
  const float* Wq_up    = (const float*)d_in[5];
  const float* Wkv_down = (const float*)d_in[6];
  const float* kv_gamma = (const float*)d_in[7];
  const float* Wkv_up   = (const float*)d_in[8];
  const float* Wo       = (const float*)d_in[9];
  float* out = (float*)d_out;

  // ---- workspace (134 MB, aliased; liveness as rounds 5-8 + Vrow) ----
  char* base = (char*)d_ws;
  short* hb  = (short*)base;
  float* kvf = (float*)(base + 16777216);
  short* Qb  = (short*)base;
  char* pB = base + 27262976;
  short* Wqd_b  = (short*)pB;
  short* Wkvd_b = (short*)(pB + 6291456);
  short* Wqu_b  = (short*)(pB + 8912896);
  short* Wkvu_b = (short*)(pB + 18350080);
  short* Wo_b   = (short*)(pB + 22544384);
  char* pC = pB + 30932992;
  float* q_lat = (float*)pC;
  short* Kb    = (short*)pC;
  char* pD = pC + 25165824;
  short* q_lat_b = (short*)pD;
  short* ckv_b   = (short*)(pD + 12582912);
  short* krope_b = (short*)(pD + 16777216);
  short* attn_b  = (short*)pD;
  char* pE = pD + 17301504;
  short* Vt   = (short*)pE;                       // 16.78 MB
  short* Vrow = (short*)(pE + 16777216);          // 16.78 MB

  dim3 blk(256);

  cast_all<<<23296, blk, 0, stream>>>(hidden, Wq_down, Wq_up, Wkv_up, Wo, Wkv_down,
                                      hb, Wqd_b, Wqu_b, Wkvu_b, Wo_b, Wkvd_b);

  gemm_mfma<0><<<dim3(12, 32), blk, 0, stream>>>(hb, Wqd_b, q_lat, 1536, 2048, nullptr, nullptr, nullptr);
  gemm_mfma<0><<<dim3(5, 32), blk, 0, stream>>>(hb, Wkvd_b, kvf, 640, 2048, nullptr, nullptr, nullptr);

  rmsnorm_cast<<<4096, blk, 0, stream>>>(q_lat, q_gamma, q_lat_b, 1536, 1536, 1536);
  rmsnorm_kv_rope<<<4096, blk, 0, stream>>>(kvf, kv_gamma, cosb, sinb, ckv_b, krope_b);

  gemm_mfma<2><<<dim3(24, 32), blk, 0, stream>>>(q_lat_b, Wqu_b, Qb, 3072, 1536, cosb, sinb, nullptr);
  gemm_mfma<3><<<dim3(32, 32), blk, 0, stream>>>(ckv_b, Wkvu_b, Kb, 4096, 512, nullptr, nullptr, Vrow);
  pack_vt<<<dim3(64, 4, 32), blk, 0, stream>>>(Vrow, Vt);
  krope_fill<<<4096, blk, 0, stream>>>(krope_b, Kb);

  flash_mfma<<<dim3(16, 16, 2), dim3(128), 0, stream>>>(Qb, Kb, Vt, attn_b);
  gemm_mfma<0><<<dim3(16, 32), blk, 0, stream>>>(attn_b, Wo_b, out, 2048, 2048, nullptr, nullptr, nullptr);
}